// Round 11
// baseline (379.586 us; speedup 1.0000x reference)
//
#include <hip/hip_runtime.h>
#include <math.h>

#define E_TOTAL 100000
#define N_TILES 6250   // E_TOTAL / 16

typedef __attribute__((ext_vector_type(4))) float f32x4;
typedef __attribute__((ext_vector_type(8))) short bf16x8;

__device__ unsigned short g_fc2H[36864];   // bf16 weights: [col*16 + k]

__device__ __forceinline__ unsigned short f2bf(float x) {
  unsigned int u = __float_as_uint(x);
  u += 0x7fffu + ((u >> 16) & 1u);      // round-to-nearest-even
  return (unsigned short)(u >> 16);
}
__device__ __forceinline__ float bf2f(unsigned short h) {
  return __uint_as_float(((unsigned int)h) << 16);
}

// fc2F[col][k] = fc_w2[k][col] * 0.25f (fp32), col in [0,2304), k in [0,16).
__global__ void prep_fc2_kernel(const float* __restrict__ fw2,
                                float* __restrict__ fc2F) {
  int tid = blockIdx.x * 256 + threadIdx.x;   // 144*256 = 36864 exactly
  int col = tid >> 4;
  int k   = tid & 15;
  fc2F[col * 16 + k] = fw2[k * 2304 + col] * 0.25f;   // fc_w2 / sqrt(HID=16)
}

// Same values rounded to bf16, into device-global (no extra workspace needed).
__global__ void prep_fc2h_kernel(const float* __restrict__ fw2) {
  int tid = blockIdx.x * 256 + threadIdx.x;
  int col = tid >> 4;
  int k   = tid & 15;
  g_fc2H[tid] = f2bf(fw2[k * 2304 + col] * 0.25f);    // tid == col*16+k
}

// ============ tp_kernel: EXACT R7 (best passing, 146us counter) ============
__global__ __launch_bounds__(256) void tp_kernel(
    const float* __restrict__ feature,   // (20000, 80)
    const int*   __restrict__ edge,      // (2, 100000)
    const float* __restrict__ elem,      // (100000, 10)
    const float* __restrict__ esh,       // (100000, 4)
    const float* __restrict__ fw1,       // (10, 16)
    const float* __restrict__ fc2F,      // (2304, 16) fp32, pre-scaled
    float* __restrict__ out,             // (100000, 80)
    float silu_c)
{
  __shared__ __align__(16) float fc1s[160];
  __shared__ __align__(16) float s1T[4][32][20];
  __shared__ __align__(16) float v1T[4][16][3][20];
  __shared__ __align__(16) float dT[4][16][16];
  __shared__ __align__(16) float s2A[4][16];
  __shared__ __align__(16) float v2A[4][3][16];
  __shared__ __align__(16) float elemL[4][160];
  __shared__ __align__(16) float hF[4][16][16];
  __shared__ int dstA[4][16];
  __shared__ __align__(16) float wbufF[2][48 * 20];

  const int tid    = threadIdx.x;
  const int wid    = tid >> 6;
  const int l      = tid & 63;
  const int lane16 = l & 15;
  const int quad   = l >> 4;
  const int quad4  = quad * 4;

  int tile = blockIdx.x * 4 + wid;
  if (tile >= N_TILES) tile = N_TILES - 1;
  const int eg0 = tile * 16;

  if (tid < 160) fc1s[tid] = fw1[tid] / sqrtf(10.0f);
  if (l < 16) dstA[wid][l] = edge[E_TOTAL + eg0 + l];
  elemL[wid][l] = elem[eg0 * 10 + l];
  elemL[wid][64 + l] = elem[eg0 * 10 + 64 + l];
  if (l < 32) elemL[wid][128 + l] = elem[eg0 * 10 + 128 + l];
  {
    float v = esh[eg0 * 4 + l];
    int e = l >> 2, c = l & 3;
    if (c == 0) s2A[wid][e] = v;
    else        v2A[wid][c - 1][e] = v;
  }
  __syncthreads();

  {
    const int c0 = l;
    const int u0 = (c0 - 32) / 3, i0 = (c0 - 32) % 3;
    #pragma unroll 4
    for (int e = 0; e < 16; ++e) {
      int base = dstA[wid][e] * 80;
      float v = feature[base + c0];
      if (c0 < 32) s1T[wid][c0][e] = v;
      else         v1T[wid][u0][i0][e] = v;
    }
    if (l < 16) {
      const int c1 = 64 + l;
      const int u1 = (c1 - 32) / 3, i1 = (c1 - 32) % 3;
      for (int e = 0; e < 16; ++e) {
        int base = dstA[wid][e] * 80;
        v1T[wid][u1][i1][e] = feature[base + c1];
      }
    }
  }
  __syncthreads();

  {
    const int e = lane16;
    #pragma unroll
    for (int q = 0; q < 4; ++q) {
      int k = quad + 4 * q;
      float a = 0.f;
      #pragma unroll
      for (int j = 0; j < 10; ++j)
        a = fmaf(elemL[wid][e * 10 + j], fc1s[j * 16 + k], a);
      hF[wid][e][k] = silu_c * a / (1.f + __expf(-a));
    }
    #pragma unroll
    for (int q = 0; q < 4; ++q) {
      int u = quad + 4 * q;
      dT[wid][u][e] = v1T[wid][u][0][e] * v2A[wid][0][e]
                    + v1T[wid][u][1][e] * v2A[wid][1][e]
                    + v1T[wid][u][2][e] * v2A[wid][2][e];
    }
  }
  __syncthreads();

  float hr[4][16];
  #pragma unroll
  for (int r = 0; r < 4; ++r)
    #pragma unroll
    for (int k = 0; k < 16; ++k)
      hr[r][k] = hF[wid][quad4 + r][k];

  const f32x4 zero4 = {0.f, 0.f, 0.f, 0.f};
  f32x4 as0a = zero4, as0b = zero4, at1 = zero4, as3a = zero4, as3b = zero4;
  f32x4 at2a = zero4, at2b = zero4, at2c = zero4;

  const int wrow0 = (tid >> 4) * 20 + (tid & 15);
  const int wrow1 = wrow0 + 16 * 20;
  const int wrow2 = wrow0 + 32 * 20;

  {
    float g0 = fc2F[tid];
    float g1 = fc2F[256 + tid];
    float g2 = fc2F[16384 + tid];
    wbufF[0][wrow0] = g0;
    wbufF[0][wrow1] = g1;
    wbufF[0][wrow2] = g2;
  }
  __syncthreads();

  #pragma unroll 1
  for (int u = 0; u < 32; ++u) {
    float g0, g1, g2;
    {
      int un = u + 1;
      if (un < 32) {
        g0 = fc2F[un * 512 + tid];
        g1 = fc2F[un * 512 + 256 + tid];
        g2 = fc2F[16384 + un * 256 + tid];
      } else {
        g0 = fc2F[24576 + tid];
        g1 = fc2F[28672 + tid];
        g2 = fc2F[28672 + 256 + tid];
      }
    }

    const float* L0 = &wbufF[u & 1][lane16 * 20];
    const float* L1 = L0 + 16 * 20;
    const float* L2 = L0 + 32 * 20;
    f32x4 d0 = zero4, d1 = zero4, d2 = zero4;
    #pragma unroll
    for (int kk = 0; kk < 4; ++kk) {
      f32x4 x0 = *(const f32x4*)(L0 + 4 * kk);
      f32x4 x1 = *(const f32x4*)(L1 + 4 * kk);
      f32x4 x2 = *(const f32x4*)(L2 + 4 * kk);
      #pragma unroll
      for (int j = 0; j < 4; ++j) {
        const int k = kk * 4 + j;
        #pragma unroll
        for (int r = 0; r < 4; ++r) {
          d0[r] = fmaf(hr[r][k], x0[j], d0[r]);
          d1[r] = fmaf(hr[r][k], x1[j], d1[r]);
          d2[r] = fmaf(hr[r][k], x2[j], d2[r]);
        }
      }
    }
    f32x4 s1v = *(const f32x4*)&s1T[wid][u][quad4];
    as0a += d0 * s1v;
    as0b += d1 * s1v;
    at1  += d2 * s1v;

    float* W = wbufF[(u + 1) & 1];
    W[wrow0] = g0;
    W[wrow1] = g1;
    W[wrow2] = g2;
    __syncthreads();
  }

  #pragma unroll 1
  for (int v = 0; v < 16; ++v) {
    float g0 = 0.f, g1 = 0.f, g2 = 0.f;
    if (v < 15) {
      int vn = v + 1;
      g0 = fc2F[24576 + vn * 256 + tid];
      g1 = fc2F[28672 + vn * 512 + tid];
      g2 = fc2F[28672 + vn * 512 + 256 + tid];
    }

    const float* L0 = &wbufF[v & 1][lane16 * 20];
    const float* L1 = L0 + 16 * 20;
    const float* L2 = L0 + 32 * 20;
    f32x4 dw2 = zero4, d3a = zero4, d3b = zero4;
    #pragma unroll
    for (int kk = 0; kk < 4; ++kk) {
      f32x4 y0 = *(const f32x4*)(L0 + 4 * kk);
      f32x4 y1 = *(const f32x4*)(L1 + 4 * kk);
      f32x4 y2 = *(const f32x4*)(L2 + 4 * kk);
      #pragma unroll
      for (int j = 0; j < 4; ++j) {
        const int k = kk * 4 + j;
        #pragma unroll
        for (int r = 0; r < 4; ++r) {
          dw2[r] = fmaf(hr[r][k], y0[j], dw2[r]);
          d3a[r] = fmaf(hr[r][k], y1[j], d3a[r]);
          d3b[r] = fmaf(hr[r][k], y2[j], d3b[r]);
        }
      }
    }
    f32x4 v1v0 = *(const f32x4*)&v1T[wid][v][0][quad4];
    f32x4 v1v1 = *(const f32x4*)&v1T[wid][v][1][quad4];
    f32x4 v1v2 = *(const f32x4*)&v1T[wid][v][2][quad4];
    at2a += dw2 * v1v0;
    at2b += dw2 * v1v1;
    at2c += dw2 * v1v2;
    f32x4 dv = *(const f32x4*)&dT[wid][v][quad4];
    as3a += d3a * dv;
    as3b += d3b * dv;

    if (v < 15) {
      float* W = wbufF[(v + 1) & 1];
      W[wrow0] = g0;
      W[wrow1] = g1;
      W[wrow2] = g2;
      __syncthreads();
    }
  }

  f32x4 s2v = *(const f32x4*)&s2A[wid][quad4];
  f32x4 v20 = *(const f32x4*)&v2A[wid][0][quad4];
  f32x4 v21 = *(const f32x4*)&v2A[wid][1][quad4];
  f32x4 v22 = *(const f32x4*)&v2A[wid][2][quad4];
  const float CC = 0.14433756729740643f;
  #pragma unroll
  for (int r = 0; r < 4; ++r) {
    int e = eg0 + quad4 + r;
    float* op = out + (size_t)e * 80;
    op[lane16]      = CC * s2v[r] * as0a[r] + 0.25f * as3a[r];
    op[16 + lane16] = CC * s2v[r] * as0b[r] + 0.25f * as3b[r];
    float t1r = at1[r];
    float* vp = op + 32 + lane16 * 3;
    vp[0] = CC * (v20[r] * t1r + s2v[r] * at2a[r]);
    vp[1] = CC * (v21[r] * t1r + s2v[r] * at2b[r]);
    vp[2] = CC * (v22[r] * t1r + s2v[r] * at2c[r]);
  }
}

// ============ probe_kernel: 1 wave, tile 0; replicates R10's MFMA loops
// with VECTOR bf16x8 loads from g_fc2H and compares vs fp32 refs computed
// with bf16-ROUNDED weights (layout-sharp, tol 0.02).
// marker: 0.04 (ran,clean) / 0.09 (loop1 bad) / 0.15 (loop1 ok, loop2 bad).
__global__ void probe_kernel(
    const float* __restrict__ feature, const int* __restrict__ edge,
    const float* __restrict__ elem,    const float* __restrict__ esh,
    const float* __restrict__ fw1,     const float* __restrict__ fc2F,
    float* __restrict__ out, float silu_c)
{
  __shared__ float fc1P[160], elemP[160];
  __shared__ float s1P[32][20], v1P[16][3][20], dP[16][16], hP[16][16];
  __shared__ float s2P[16], v2P[3][16];
  __shared__ int dstP[16];

  const int l = threadIdx.x;          // 64 threads
  const int lane16 = l & 15;
  const int quad   = l >> 4;
  const int quad4  = quad * 4;

  for (int i = l; i < 160; i += 64) { fc1P[i] = fw1[i] / sqrtf(10.0f); elemP[i] = elem[i]; }
  if (l < 16) dstP[l] = edge[E_TOTAL + l];
  {
    float v = esh[l];
    int e = l >> 2, c = l & 3;
    if (c == 0) s2P[e] = v; else v2P[c - 1][e] = v;
  }
  __syncthreads();
  {
    const int c0 = l;
    const int u0 = (c0 - 32) / 3, i0 = (c0 - 32) % 3;
    for (int e = 0; e < 16; ++e) {
      int base = dstP[e] * 80;
      float v = feature[base + c0];
      if (c0 < 32) s1P[c0][e] = v; else v1P[u0][i0][e] = v;
    }
    if (l < 16) {
      const int c1 = 64 + l;
      const int u1 = (c1 - 32) / 3, i1 = (c1 - 32) % 3;
      for (int e = 0; e < 16; ++e)
        v1P[u1][i1][e] = feature[dstP[e] * 80 + c1];
    }
  }
  __syncthreads();
  {
    const int e = lane16;
    for (int q = 0; q < 4; ++q) {
      int k = quad + 4 * q;
      float a = 0.f;
      for (int j = 0; j < 10; ++j) a = fmaf(elemP[e * 10 + j], fc1P[j * 16 + k], a);
      hP[e][k] = silu_c * a / (1.f + __expf(-a));
    }
    for (int q = 0; q < 4; ++q) {
      int u = quad + 4 * q;
      dP[u][e] = v1P[u][0][e] * v2P[0][e] + v1P[u][1][e] * v2P[1][e]
               + v1P[u][2][e] * v2P[2][e];
    }
  }
  __syncthreads();

  float hr[4][16];
  for (int r = 0; r < 4; ++r)
    for (int k = 0; k < 16; ++k) hr[r][k] = hP[quad4 + r][k];

  bf16x8 afrag;
  {
    const int k0 = (quad & 1) * 8;
    const bool lo_half = (quad >= 2);
    for (int i = 0; i < 8; ++i) {
      float hv = hP[lane16][k0 + i];
      unsigned short hi = f2bf(hv);
      afrag[i] = (short)(lo_half ? f2bf(hv - bf2f(hi)) : hi);
    }
  }

  const f32x4 zero4 = {0.f, 0.f, 0.f, 0.f};
  const unsigned int* FU  = (const unsigned int*)g_fc2H;
  const unsigned int* FUq = FU + lane16 * 8 + (quad & 1) * 4;

  int badA = 0, badB = 0;
  // ---- loop 1 (W0/W1): fp32 ref w/ rounded weights vs MFMA vector-load ----
  {
    f32x4 r0 = zero4, r1 = zero4, r2 = zero4;
    f32x4 m0 = zero4, m1 = zero4, m2 = zero4;
    for (int s = 0; s < 32; ++s) {
      const float* B0 = fc2F + (s * 32 + lane16) * 16;
      const float* B1 = B0 + 256;
      const float* B2 = fc2F + (1024 + s * 16 + lane16) * 16;
      f32x4 d0 = zero4, d1 = zero4, d2 = zero4;
      for (int k = 0; k < 16; ++k) {
        float x0 = bf2f(f2bf(B0[k])), x1 = bf2f(f2bf(B1[k])), x2 = bf2f(f2bf(B2[k]));
        for (int r = 0; r < 4; ++r) {
          d0[r] = fmaf(hr[r][k], x0, d0[r]);
          d1[r] = fmaf(hr[r][k], x1, d1[r]);
          d2[r] = fmaf(hr[r][k], x2, d2[r]);
        }
      }
      bf16x8 b0 = *(const bf16x8*)(FUq + s * 256);
      bf16x8 b1 = *(const bf16x8*)(FUq + s * 256 + 128);
      bf16x8 b2 = *(const bf16x8*)(FUq + 8192 + s * 128);
      f32x4 e0 = __builtin_amdgcn_mfma_f32_16x16x32_bf16(afrag, b0, zero4, 0, 0, 0);
      f32x4 e1 = __builtin_amdgcn_mfma_f32_16x16x32_bf16(afrag, b1, zero4, 0, 0, 0);
      f32x4 e2 = __builtin_amdgcn_mfma_f32_16x16x32_bf16(afrag, b2, zero4, 0, 0, 0);
      f32x4 s1v = *(const f32x4*)&s1P[s][quad4];
      r0 += d0 * s1v; r1 += d1 * s1v; r2 += d2 * s1v;
      m0 += e0 * s1v; m1 += e1 * s1v; m2 += e2 * s1v;
    }
    for (int r = 0; r < 4; ++r) {
      if (fabsf(m0[r] - r0[r]) > 0.02f) badA = 1;
      if (fabsf(m1[r] - r1[r]) > 0.02f) badA = 1;
      if (fabsf(m2[r] - r2[r]) > 0.02f) badA = 1;
    }
  }
  // ---- loop 2 (W2/W3) ----
  {
    f32x4 ra = zero4, rb = zero4, rc = zero4;
    f32x4 ma = zero4, mb = zero4, mc = zero4;
    for (int v = 0; v < 16; ++v) {
      const float* B0 = fc2F + (1536 + v * 16 + lane16) * 16;
      const float* B1 = fc2F + (1792 + v * 32 + lane16) * 16;
      const float* B2 = B1 + 256;
      f32x4 d0 = zero4, d1 = zero4, d2 = zero4;
      for (int k = 0; k < 16; ++k) {
        float x0 = bf2f(f2bf(B0[k])), x1 = bf2f(f2bf(B1[k])), x2 = bf2f(f2bf(B2[k]));
        for (int r = 0; r < 4; ++r) {
          d0[r] = fmaf(hr[r][k], x0, d0[r]);
          d1[r] = fmaf(hr[r][k], x1, d1[r]);
          d2[r] = fmaf(hr[r][k], x2, d2[r]);
        }
      }
      bf16x8 b0 = *(const bf16x8*)(FUq + 12288 + v * 128);
      bf16x8 b1 = *(const bf16x8*)(FUq + 14336 + v * 256);
      bf16x8 b2 = *(const bf16x8*)(FUq + 14336 + v * 256 + 128);
      f32x4 e0 = __builtin_amdgcn_mfma_f32_16x16x32_bf16(afrag, b0, zero4, 0, 0, 0);
      f32x4 e1 = __builtin_amdgcn_mfma_f32_16x16x32_bf16(afrag, b1, zero4, 0, 0, 0);
      f32x4 e2 = __builtin_amdgcn_mfma_f32_16x16x32_bf16(afrag, b2, zero4, 0, 0, 0);
      f32x4 v1v0 = *(const f32x4*)&v1P[v][0][quad4];
      f32x4 dv   = *(const f32x4*)&dP[v][quad4];
      ra += d0 * v1v0; rb += d1 * dv; rc += d2 * dv;
      ma += e0 * v1v0; mb += e1 * dv; mc += e2 * dv;
    }
    for (int r = 0; r < 4; ++r) {
      if (fabsf(ma[r] - ra[r]) > 0.02f) badB = 1;
      if (fabsf(mb[r] - rb[r]) > 0.02f) badB = 1;
      if (fabsf(mc[r] - rc[r]) > 0.02f) badB = 1;
    }
  }

  float marker = 0.04f + (__any(badA) ? 0.05f : (__any(badB) ? 0.11f : 0.f));
  if (quad == 0) out[lane16] += marker;   // edge 0, scalar cols 0..15
}

extern "C" void kernel_launch(void* const* d_in, const int* in_sizes, int n_in,
                              void* d_out, int out_size, void* d_ws, size_t ws_size,
                              hipStream_t stream) {
  const float* feature = (const float*)d_in[0];
  const int*   edge    = (const int*)d_in[1];
  const float* elem    = (const float*)d_in[2];
  const float* esh     = (const float*)d_in[3];
  const float* fw1     = (const float*)d_in[4];
  const float* fw2     = (const float*)d_in[5];
  float* out = (float*)d_out;
  float* fc2F = (float*)d_ws;   // 2304*16*4 B = 147456 B

  const int NPTS = 200001;
  const double dx = 24.0 / 200000.0;
  const double inv_sqrt2pi = 0.3989422804014326779;
  double sum = 0.0;
  double x0 = -12.0;
  double s0 = x0 / (1.0 + exp(-x0));
  double y0 = s0 * s0 * exp(-0.5 * x0 * x0) * inv_sqrt2pi;
  for (int i = 1; i < NPTS; ++i) {
    double x1 = -12.0 + i * dx;
    double s1 = x1 / (1.0 + exp(-x1));
    double y1 = s1 * s1 * exp(-0.5 * x1 * x1) * inv_sqrt2pi;
    sum += 0.5 * (y0 + y1) * dx;
    y0 = y1;
  }
  float silu_c = (float)(1.0 / sqrt(sum));

  hipLaunchKernelGGL(prep_fc2_kernel, dim3(144), dim3(256), 0, stream, fw2, fc2F);
  hipLaunchKernelGGL(prep_fc2h_kernel, dim3(144), dim3(256), 0, stream, fw2);
  hipLaunchKernelGGL(tp_kernel, dim3(1563), dim3(256), 0, stream,
                     feature, edge, elem, esh, fw1, fc2F, out, silu_c);
  hipLaunchKernelGGL(probe_kernel, dim3(1), dim3(64), 0, stream,
                     feature, edge, elem, esh, fw1, fc2F, out, silu_c);
}

// Round 12
// 222.237 us; speedup vs baseline: 1.7080x; 1.7080x over previous
//
#include <hip/hip_runtime.h>
#include <math.h>

#define E_TOTAL 100000
#define N_TILES 6250   // E_TOTAL / 16

typedef __attribute__((ext_vector_type(4))) float f32x4;
typedef __attribute__((ext_vector_type(8))) short bf16x8;

__device__ unsigned short g_fc2H[36864];   // bf16 weights: [col*16 + k]

__device__ __forceinline__ unsigned short f2bf(float x) {
  unsigned int u = __float_as_uint(x);
  u += 0x7fffu + ((u >> 16) & 1u);      // round-to-nearest-even
  return (unsigned short)(u >> 16);
}
__device__ __forceinline__ float bf2f(unsigned short h) {
  return __uint_as_float(((unsigned int)h) << 16);
}

// g_fc2H[col*16 + k] = bf16(fc_w2[k][col] * 0.25f)  (R11-probe-verified source)
__global__ void prep_fc2h_kernel(const float* __restrict__ fw2) {
  int tid = blockIdx.x * 256 + threadIdx.x;   // 144*256 = 36864 exactly
  int col = tid >> 4;
  int k   = tid & 15;
  g_fc2H[tid] = f2bf(fw2[k * 2304 + col] * 0.25f);    // tid == col*16+k
}

// ===== Production kernel = R11 probe_kernel promoted: 1 wave / 16-edge tile.
// Everything structural (staging, afrag, FUq, MFMA loops, no unroll pragmas,
// device-global weights) matches the HW-verified probe configuration.
__global__ __launch_bounds__(64) void tp_kernel(
    const float* __restrict__ feature,   // (20000, 80)
    const int*   __restrict__ edge,      // (2, 100000)
    const float* __restrict__ elem,      // (100000, 10)
    const float* __restrict__ esh,       // (100000, 4)
    const float* __restrict__ fw1,       // (10, 16)
    float* __restrict__ out,             // (100000, 80)
    float silu_c)
{
  __shared__ float fc1P[160], elemP[160];
  __shared__ __align__(16) float s1P[32][20];
  __shared__ __align__(16) float v1P[16][3][20];
  __shared__ __align__(16) float dP[16][16];
  __shared__ __align__(16) float hP[16][16];
  __shared__ float s2P[16], v2P[3][16];
  __shared__ int dstP[16];

  const int l      = threadIdx.x;       // 64 threads = 1 wave
  const int lane16 = l & 15;
  const int quad   = l >> 4;
  const int quad4  = quad * 4;
  const int eg0    = blockIdx.x * 16;   // grid = 6250 exactly

  // ---- stage per-tile inputs (probe-verbatim, offset by eg0) ----
  for (int i = l; i < 160; i += 64) {
    fc1P[i]  = fw1[i] / sqrtf(10.0f);
    elemP[i] = elem[eg0 * 10 + i];
  }
  if (l < 16) dstP[l] = edge[E_TOTAL + eg0 + l];
  {
    float v = esh[eg0 * 4 + l];
    int e = l >> 2, c = l & 3;
    if (c == 0) s2P[e] = v; else v2P[c - 1][e] = v;
  }
  __syncthreads();

  // ---- feature gather: lane = channel, loop edges (probe-verbatim) ----
  {
    const int c0 = l;
    const int u0 = (c0 - 32) / 3, i0 = (c0 - 32) % 3;
    for (int e = 0; e < 16; ++e) {
      int base = dstP[e] * 80;
      float v = feature[base + c0];
      if (c0 < 32) s1P[c0][e] = v; else v1P[u0][i0][e] = v;
    }
    if (l < 16) {
      const int c1 = 64 + l;
      const int u1 = (c1 - 32) / 3, i1 = (c1 - 32) % 3;
      for (int e = 0; e < 16; ++e)
        v1P[u1][i1][e] = feature[dstP[e] * 80 + c1];
    }
  }
  __syncthreads();

  // ---- h = SILU_C * silu(elem @ fc1) ; dP[u][e] = v1[u,:].v2 (probe-verbatim) ----
  {
    const int e = lane16;
    for (int q = 0; q < 4; ++q) {
      int k = quad + 4 * q;
      float a = 0.f;
      for (int j = 0; j < 10; ++j)
        a = fmaf(elemP[e * 10 + j], fc1P[j * 16 + k], a);
      hP[e][k] = silu_c * a / (1.f + __expf(-a));
    }
    for (int q = 0; q < 4; ++q) {
      int u = quad + 4 * q;
      dP[u][e] = v1P[u][0][e] * v2P[0][e] + v1P[u][1][e] * v2P[1][e]
               + v1P[u][2][e] * v2P[2][e];
    }
  }
  __syncthreads();

  // ---- A fragment (probe-verbatim): [hi(h)0..15 | lo(h)0..15], chunk by quad ----
  bf16x8 afrag;
  {
    const int k0 = (quad & 1) * 8;
    const bool lo_half = (quad >= 2);
    for (int i = 0; i < 8; ++i) {
      float hv = hP[lane16][k0 + i];
      unsigned short hi = f2bf(hv);
      afrag[i] = (short)(lo_half ? f2bf(hv - bf2f(hi)) : hi);
    }
  }

  const f32x4 zero4 = {0.f, 0.f, 0.f, 0.f};
  const unsigned int* FU  = (const unsigned int*)g_fc2H;
  const unsigned int* FUq = FU + lane16 * 8 + (quad & 1) * 4;

  f32x4 as0a = zero4, as0b = zero4, at1 = zero4, as3a = zero4, as3b = zero4;
  f32x4 at2a = zero4, at2b = zero4, at2c = zero4;

  // ---- loop 1 (W0/W1), probe-verbatim addressing, no unroll pragma ----
  for (int s = 0; s < 32; ++s) {
    bf16x8 b0 = *(const bf16x8*)(FUq + s * 256);           // W0 col s*32+lane16
    bf16x8 b1 = *(const bf16x8*)(FUq + s * 256 + 128);     // W0 col +16
    bf16x8 b2 = *(const bf16x8*)(FUq + 8192 + s * 128);    // W1 col 1024+s*16+lane16
    f32x4 e0 = __builtin_amdgcn_mfma_f32_16x16x32_bf16(afrag, b0, zero4, 0, 0, 0);
    f32x4 e1 = __builtin_amdgcn_mfma_f32_16x16x32_bf16(afrag, b1, zero4, 0, 0, 0);
    f32x4 e2 = __builtin_amdgcn_mfma_f32_16x16x32_bf16(afrag, b2, zero4, 0, 0, 0);
    f32x4 s1v = *(const f32x4*)&s1P[s][quad4];
    as0a += e0 * s1v;     // d[r] = W[edge=quad4+r][col]  (R8+R11 verified)
    as0b += e1 * s1v;
    at1  += e2 * s1v;
  }

  // ---- loop 2 (W2/W3), probe-verbatim ----
  for (int v = 0; v < 16; ++v) {
    bf16x8 b0 = *(const bf16x8*)(FUq + 12288 + v * 128);         // W2
    bf16x8 b1 = *(const bf16x8*)(FUq + 14336 + v * 256);         // W3 lo16
    bf16x8 b2 = *(const bf16x8*)(FUq + 14336 + v * 256 + 128);   // W3 hi16
    f32x4 e0 = __builtin_amdgcn_mfma_f32_16x16x32_bf16(afrag, b0, zero4, 0, 0, 0);
    f32x4 e1 = __builtin_amdgcn_mfma_f32_16x16x32_bf16(afrag, b1, zero4, 0, 0, 0);
    f32x4 e2 = __builtin_amdgcn_mfma_f32_16x16x32_bf16(afrag, b2, zero4, 0, 0, 0);
    f32x4 v1v0 = *(const f32x4*)&v1P[v][0][quad4];
    f32x4 v1v1 = *(const f32x4*)&v1P[v][1][quad4];
    f32x4 v1v2 = *(const f32x4*)&v1P[v][2][quad4];
    f32x4 dv   = *(const f32x4*)&dP[v][quad4];
    at2a += e0 * v1v0;
    at2b += e0 * v1v1;
    at2c += e0 * v1v2;
    as3a += e1 * dv;
    as3b += e2 * dv;
  }

  // ---- epilogue (R7-verbatim frame) ----
  f32x4 s2v = *(const f32x4*)&s2P[quad4];
  f32x4 v20 = *(const f32x4*)&v2P[0][quad4];
  f32x4 v21 = *(const f32x4*)&v2P[1][quad4];
  f32x4 v22 = *(const f32x4*)&v2P[2][quad4];
  const float CC = 0.14433756729740643f;  // 1/sqrt(48) = C0 = C1 = C2; C3 = 0.25
  for (int r = 0; r < 4; ++r) {
    int e = eg0 + quad4 + r;
    float* op = out + (size_t)e * 80;
    op[lane16]      = CC * s2v[r] * as0a[r] + 0.25f * as3a[r];
    op[16 + lane16] = CC * s2v[r] * as0b[r] + 0.25f * as3b[r];
    float t1r = at1[r];
    float* vp = op + 32 + lane16 * 3;
    vp[0] = CC * (v20[r] * t1r + s2v[r] * at2a[r]);
    vp[1] = CC * (v21[r] * t1r + s2v[r] * at2b[r]);
    vp[2] = CC * (v22[r] * t1r + s2v[r] * at2c[r]);
  }
}

extern "C" void kernel_launch(void* const* d_in, const int* in_sizes, int n_in,
                              void* d_out, int out_size, void* d_ws, size_t ws_size,
                              hipStream_t stream) {
  const float* feature = (const float*)d_in[0];
  const int*   edge    = (const int*)d_in[1];
  const float* elem    = (const float*)d_in[2];
  const float* esh     = (const float*)d_in[3];
  const float* fw1     = (const float*)d_in[4];
  const float* fw2     = (const float*)d_in[5];
  float* out = (float*)d_out;
  (void)d_ws; (void)ws_size;

  // SILU_C: replicate np.trapz(silu(x)^2 * N(0,1) pdf, 200001 pts on [-12,12])
  const int NPTS = 200001;
  const double dx = 24.0 / 200000.0;
  const double inv_sqrt2pi = 0.3989422804014326779;
  double sum = 0.0;
  double x0 = -12.0;
  double s0 = x0 / (1.0 + exp(-x0));
  double y0 = s0 * s0 * exp(-0.5 * x0 * x0) * inv_sqrt2pi;
  for (int i = 1; i < NPTS; ++i) {
    double x1 = -12.0 + i * dx;
    double s1 = x1 / (1.0 + exp(-x1));
    double y1 = s1 * s1 * exp(-0.5 * x1 * x1) * inv_sqrt2pi;
    sum += 0.5 * (y0 + y1) * dx;
    y0 = y1;
  }
  float silu_c = (float)(1.0 / sqrt(sum));

  hipLaunchKernelGGL(prep_fc2h_kernel, dim3(144), dim3(256), 0, stream, fw2);
  hipLaunchKernelGGL(tp_kernel, dim3(N_TILES), dim3(64), 0, stream,
                     feature, edge, elem, esh, fw1, out, silu_c);
}

// Round 15
// 124.232 us; speedup vs baseline: 3.0555x; 1.7889x over previous
//
#include <hip/hip_runtime.h>
#include <math.h>

#define E_TOTAL 100000
#define N_TILES 6250   // E_TOTAL / 16

typedef __attribute__((ext_vector_type(4))) float f32x4;
typedef __attribute__((ext_vector_type(8))) short bf16x8;

__device__ unsigned short g_fc2H[36864];   // bf16 weights: [col*16 + k]

__device__ __forceinline__ unsigned short f2bf(float x) {
  unsigned int u = __float_as_uint(x);
  u += 0x7fffu + ((u >> 16) & 1u);      // round-to-nearest-even
  return (unsigned short)(u >> 16);
}
__device__ __forceinline__ float bf2f(unsigned short h) {
  return __uint_as_float(((unsigned int)h) << 16);
}

// g_fc2H[col*16 + k] = bf16(fc_w2[k][col] * 0.25f)  (R11-probe-verified source)
__global__ void prep_fc2h_kernel(const float* __restrict__ fw2) {
  int tid = blockIdx.x * 256 + threadIdx.x;   // 144*256 = 36864 exactly
  int col = tid >> 4;
  int k   = tid & 15;
  g_fc2H[tid] = f2bf(fw2[k * 2304 + col] * 0.25f);    // tid == col*16+k
}

// ===== R14 GPU side verbatim (passed absmax; failed only the host-time
// tripwire). Runtime loop bounds (n1=32, n2=16) prevent the full unroll that
// spilled in R12, with NO unroll pragma on MFMA loops (R13: pragma->miscompile).
__global__ __launch_bounds__(64) void tp_kernel(
    const float* __restrict__ feature,   // (20000, 80)
    const int*   __restrict__ edge,      // (2, 100000)
    const float* __restrict__ elem,      // (100000, 10)
    const float* __restrict__ esh,       // (100000, 4)
    const float* __restrict__ fw1,       // (10, 16)
    float* __restrict__ out,             // (100000, 80)
    float silu_c, int n1, int n2)
{
  __shared__ float fc1P[160], elemP[160];
  __shared__ __align__(16) float s1P[32][20];
  __shared__ __align__(16) float v1P[16][3][20];
  __shared__ __align__(16) float dP[16][16];
  __shared__ __align__(16) float hP[16][16];
  __shared__ float s2P[16], v2P[3][16];
  __shared__ int dstP[16];

  const int l      = threadIdx.x;       // 64 threads = 1 wave
  const int lane16 = l & 15;
  const int quad   = l >> 4;
  const int quad4  = quad * 4;
  const int eg0    = blockIdx.x * 16;   // grid = 6250 exactly

  // ---- stage per-tile inputs ----
  for (int i = l; i < 160; i += 64) {
    fc1P[i]  = fw1[i] / sqrtf(10.0f);
    elemP[i] = elem[eg0 * 10 + i];
  }
  if (l < 16) dstP[l] = edge[E_TOTAL + eg0 + l];
  {
    float v = esh[eg0 * 4 + l];
    int e = l >> 2, c = l & 3;
    if (c == 0) s2P[e] = v; else v2P[c - 1][e] = v;
  }
  __syncthreads();

  // ---- feature gather ----
  {
    const int c0 = l;
    const int u0 = (c0 - 32) / 3, i0 = (c0 - 32) % 3;
    for (int e = 0; e < 16; ++e) {
      int base = dstP[e] * 80;
      float v = feature[base + c0];
      if (c0 < 32) s1P[c0][e] = v; else v1P[u0][i0][e] = v;
    }
    if (l < 16) {
      const int c1 = 64 + l;
      const int u1 = (c1 - 32) / 3, i1 = (c1 - 32) % 3;
      for (int e = 0; e < 16; ++e)
        v1P[u1][i1][e] = feature[dstP[e] * 80 + c1];
    }
  }
  __syncthreads();

  // ---- h = SILU_C * silu(elem @ fc1) ; dP[u][e] = v1[u,:].v2 ----
  {
    const int e = lane16;
    for (int q = 0; q < 4; ++q) {
      int k = quad + 4 * q;
      float a = 0.f;
      for (int j = 0; j < 10; ++j)
        a = fmaf(elemP[e * 10 + j], fc1P[j * 16 + k], a);
      hP[e][k] = silu_c * a / (1.f + __expf(-a));
    }
    for (int q = 0; q < 4; ++q) {
      int u = quad + 4 * q;
      dP[u][e] = v1P[u][0][e] * v2P[0][e] + v1P[u][1][e] * v2P[1][e]
               + v1P[u][2][e] * v2P[2][e];
    }
  }
  __syncthreads();

  // ---- A fragment: [hi(h)0..15 | lo(h)0..15], chunk by quad (verified) ----
  bf16x8 afrag;
  {
    const int k0 = (quad & 1) * 8;
    const bool lo_half = (quad >= 2);
    for (int i = 0; i < 8; ++i) {
      float hv = hP[lane16][k0 + i];
      unsigned short hi = f2bf(hv);
      afrag[i] = (short)(lo_half ? f2bf(hv - bf2f(hi)) : hi);
    }
  }

  const f32x4 zero4 = {0.f, 0.f, 0.f, 0.f};
  const unsigned int* FU  = (const unsigned int*)g_fc2H;
  const unsigned int* FUq = FU + lane16 * 8 + (quad & 1) * 4;

  f32x4 as0a = zero4, as0b = zero4, at1 = zero4, as3a = zero4, as3b = zero4;
  f32x4 at2a = zero4, at2b = zero4, at2c = zero4;

  // ---- loop 1 (W0/W1): runtime bound n1(=32), NO pragma ----
  for (int s = 0; s < n1; ++s) {
    bf16x8 b0 = *(const bf16x8*)(FUq + s * 256);           // W0 col s*32+lane16
    bf16x8 b1 = *(const bf16x8*)(FUq + s * 256 + 128);     // W0 col +16
    bf16x8 b2 = *(const bf16x8*)(FUq + 8192 + s * 128);    // W1 col 1024+s*16+lane16
    f32x4 e0 = __builtin_amdgcn_mfma_f32_16x16x32_bf16(afrag, b0, zero4, 0, 0, 0);
    f32x4 e1 = __builtin_amdgcn_mfma_f32_16x16x32_bf16(afrag, b1, zero4, 0, 0, 0);
    f32x4 e2 = __builtin_amdgcn_mfma_f32_16x16x32_bf16(afrag, b2, zero4, 0, 0, 0);
    f32x4 s1v = *(const f32x4*)&s1P[s][quad4];
    as0a += e0 * s1v;     // d[r] = W[edge=quad4+r][col]  (R8+R11+R12 verified)
    as0b += e1 * s1v;
    at1  += e2 * s1v;
  }

  // ---- loop 2 (W2/W3): runtime bound n2(=16), NO pragma ----
  for (int v = 0; v < n2; ++v) {
    bf16x8 b0 = *(const bf16x8*)(FUq + 12288 + v * 128);         // W2
    bf16x8 b1 = *(const bf16x8*)(FUq + 14336 + v * 256);         // W3 lo16
    bf16x8 b2 = *(const bf16x8*)(FUq + 14336 + v * 256 + 128);   // W3 hi16
    f32x4 e0 = __builtin_amdgcn_mfma_f32_16x16x32_bf16(afrag, b0, zero4, 0, 0, 0);
    f32x4 e1 = __builtin_amdgcn_mfma_f32_16x16x32_bf16(afrag, b1, zero4, 0, 0, 0);
    f32x4 e2 = __builtin_amdgcn_mfma_f32_16x16x32_bf16(afrag, b2, zero4, 0, 0, 0);
    f32x4 v1v0 = *(const f32x4*)&v1P[v][0][quad4];
    f32x4 v1v1 = *(const f32x4*)&v1P[v][1][quad4];
    f32x4 v1v2 = *(const f32x4*)&v1P[v][2][quad4];
    f32x4 dv   = *(const f32x4*)&dP[v][quad4];
    at2a += e0 * v1v0;
    at2b += e0 * v1v1;
    at2c += e0 * v1v2;
    as3a += e1 * dv;
    as3b += e2 * dv;
  }

  // ---- epilogue ----
  f32x4 s2v = *(const f32x4*)&s2P[quad4];
  f32x4 v20 = *(const f32x4*)&v2P[0][quad4];
  f32x4 v21 = *(const f32x4*)&v2P[1][quad4];
  f32x4 v22 = *(const f32x4*)&v2P[2][quad4];
  const float CC = 0.14433756729740643f;  // 1/sqrt(48) = C0 = C1 = C2; C3 = 0.25
  for (int r = 0; r < 4; ++r) {
    int e = eg0 + quad4 + r;
    float* op = out + (size_t)e * 80;
    op[lane16]      = CC * s2v[r] * as0a[r] + 0.25f * as3a[r];
    op[16 + lane16] = CC * s2v[r] * as0b[r] + 0.25f * as3b[r];
    float t1r = at1[r];
    float* vp = op + 32 + lane16 * 3;
    vp[0] = CC * (v20[r] * t1r + s2v[r] * at2a[r]);
    vp[1] = CC * (v21[r] * t1r + s2v[r] * at2b[r]);
    vp[2] = CC * (v22[r] * t1r + s2v[r] * at2c[r]);
  }
}

// Host-side SILU_C, MEMOIZED: R14's tripwire failure was ~1.2 ms of host
// exp() calls inside every kernel_launch (fresh-launch timing >> 3x replay
// once the kernel got fast). Value is identical on every call -> replayed
// GPU work and d_out are unchanged.
static float get_silu_c() {
  static float cached = -1.0f;
  if (cached < 0.0f) {
    const int NPTS = 200001;
    const double dx = 24.0 / 200000.0;
    const double inv_sqrt2pi = 0.3989422804014326779;
    double sum = 0.0;
    double x0 = -12.0;
    double s0 = x0 / (1.0 + exp(-x0));
    double y0 = s0 * s0 * exp(-0.5 * x0 * x0) * inv_sqrt2pi;
    for (int i = 1; i < NPTS; ++i) {
      double x1 = -12.0 + i * dx;
      double s1 = x1 / (1.0 + exp(-x1));
      double y1 = s1 * s1 * exp(-0.5 * x1 * x1) * inv_sqrt2pi;
      sum += 0.5 * (y0 + y1) * dx;
      y0 = y1;
    }
    cached = (float)(1.0 / sqrt(sum));
  }
  return cached;
}

extern "C" void kernel_launch(void* const* d_in, const int* in_sizes, int n_in,
                              void* d_out, int out_size, void* d_ws, size_t ws_size,
                              hipStream_t stream) {
  const float* feature = (const float*)d_in[0];
  const int*   edge    = (const int*)d_in[1];
  const float* elem    = (const float*)d_in[2];
  const float* esh     = (const float*)d_in[3];
  const float* fw1     = (const float*)d_in[4];
  const float* fw2     = (const float*)d_in[5];
  float* out = (float*)d_out;
  (void)d_ws; (void)ws_size;

  float silu_c = get_silu_c();

  hipLaunchKernelGGL(prep_fc2h_kernel, dim3(144), dim3(256), 0, stream, fw2);
  hipLaunchKernelGGL(tp_kernel, dim3(N_TILES), dim3(64), 0, stream,
                     feature, edge, elem, esh, fw1, out, silu_c, 32, 16);
}